// Round 1
// 647.652 us; speedup vs baseline: 1.0429x; 1.0429x over previous
//
#include <hip/hip_runtime.h>
#include <hip/hip_bf16.h>

// MapAgent: NatureCNN (3 convs + FC) -> map-write scan -> policy/value heads.
// T=32, B=64, TB=2048.
//
// R8 change (theory: conv1 fp32-VALU has a 64us FMA floor and ran at 160us,
// VALUBusy 49%, MfmaUtil 0; it is a GEMM M=819200 N=32 K=8taps x 24):
//  * conv1 -> implicit-GEMM fp16 MFMA, same LDS-staging pattern as
//    conv2/conv3. Each tap row = 24 contiguous NHWC floats, zero-padded to
//    K=32 (zero WEIGHT pad -> A pad is zeroed once, no NaN hazard).
//    B (8x32x32 fp16 = 16KB) lives in registers (16 half8 frags).
//  * w1 prepped as fp16 w1p[tap8][oc32][k32] with /255 folded, k=kx*3+c.
//  * conv1 output layout [li][20][20][32] fp16 unchanged -> conv2 untouched.

#define TT 32
#define BB 64
#define TBR 2048

typedef _Float16 half_t;
typedef __attribute__((ext_vector_type(8))) _Float16 half8;
typedef __attribute__((ext_vector_type(4))) float f32x4;

// ---- workspace offsets (floats) ----
#define OFF_W1T   0u          // 4096    : w1p fp16 [tap8][oc32][k32] zero-pad
#define OFF_W2T   6144u       // 16384   : w2T fp16 [tap16][oc64][c32]
#define OFF_W3T   22528u      // 18432   : w3T fp16 [tap9][oc64][c64]
#define OFF_WF    40960u      // 65536   : wfeat [2048][32]
#define OFF_PF    106496u     // 131072  : posfeat [2048][64]
#define OFF_Y0    237568u     // 8192    : y0 [64][128]
#define OFF_YS    245760u     // 262144  : ystate [2048][128]
#define OFF_H     507904u     // 1048576 : h [2048][512]
#define OFF_WFCT  1556480u    // 802816  : wfcT fp16 [512][3136] (k=c*49+pos)
#define OFF_C3    2359296u    // 3211264 : c3b fp16 [2048][3136]
#define OFF_C2    5570560u    // 5308416 : c2b fp16 [2048][9][9][64]
#define OFF_C1    10878976u   // c1b fp16 [CS][20][20][32]

// ---------------- weight prep ----------------
__global__ __launch_bounds__(256) void prep_kernel(
    const float* __restrict__ w1, const float* __restrict__ w2,
    const float* __restrict__ w3, half_t* __restrict__ w1p,
    half_t* __restrict__ w2T, half_t* __restrict__ w3T) {
  int g = blockIdx.x * 256 + threadIdx.x;   // 77824 total
  if (g < 8192) {
    // w1p[(tap*32+oc)*32+kk], kk = kx*3+c (<24) else 0 ; w1 is [oc][c][ky*8+kx]
    int kk = g & 31, oc = (g >> 5) & 31, tap = g >> 10;
    half_t v = (half_t)0.f;
    if (kk < 24) {
      int kx = kk / 3, c = kk - 3 * kx;
      v = (half_t)(w1[oc * 192 + c * 64 + tap * 8 + kx] * (1.0f / 255.0f));
    }
    w1p[g] = v;
    return;
  }
  int g2 = g - 8192;
  if (g2 < 32768) {                          // w2T[(tap*64+oc)*32+c]
    int c = g2 & 31, oc = (g2 >> 5) & 63, tap = g2 >> 11;
    w2T[g2] = (half_t)w2[oc * 512 + c * 16 + tap];
    return;
  }
  int g3 = g2 - 32768;
  if (g3 < 36864) {                          // w3T[(tap*64+oc)*64+c]
    int c = g3 & 63, oc = (g3 >> 6) & 63, tap = g3 >> 12;
    w3T[g3] = (half_t)w3[oc * 576 + c * 9 + tap];
  }
}

// ---- wfcT[n][k] = (half)wfc[k][n], k = c*49+pos : LDS-tiled transpose ----
__global__ __launch_bounds__(256) void prep_wfct(
    const float* __restrict__ wfc, half_t* __restrict__ wfcT) {
  __shared__ float t[32][33];
  int k0 = blockIdx.x * 32, n0 = blockIdx.y * 32;
  int tx = threadIdx.x & 31, ty = threadIdx.x >> 5;  // ty 0..7
#pragma unroll
  for (int i = 0; i < 4; ++i)
    t[ty + 8 * i][tx] = wfc[(size_t)(k0 + ty + 8 * i) * 512 + n0 + tx];
  __syncthreads();
#pragma unroll
  for (int i = 0; i < 4; ++i)
    wfcT[(size_t)(n0 + ty + 8 * i) * 3136 + k0 + tx] =
        (half_t)t[tx][ty + 8 * i];
}

// ---------------- conv1 implicit-GEMM MFMA: NHWC fp32 -> fp16 [li][20][20][32]
// M-tile 64 x N=32, 4 waves, 8 taps(ky) x K=32 (24 real + 8 zero-pad).
// A row (tap ky) = img[li][4oy+ky][4ox..4ox+7][:] : 24 contiguous floats,
// cast fp32->fp16 during LDS staging. B (16KB) kept in registers.
__global__ __launch_bounds__(256) void conv1_mfma(
    const float* __restrict__ img, const half_t* __restrict__ w1p,
    const float* __restrict__ b1, half_t* __restrict__ out, int n0) {
  __shared__ __align__(16) half_t As[64 * 40];
  int tid = threadIdx.x;
  int m0 = blockIdx.x * 64;
  int w = tid >> 6, l = tid & 63, lc = l & 15, q = l >> 4;
  int srow = tid >> 2, sseg = tid & 3;
  int m = m0 + srow;
  int li = m / 400, pos = m - li * 400;
  int oy = pos / 20, ox = pos - oy * 20;
  // float offset: (4oy+ky)*252 + 12*ox + 8*sseg -> multiple of 4 -> 16B aligned
  const float* aBase =
      img + (size_t)(n0 + li) * 21168 + (4 * oy) * 252 + ox * 12 + sseg * 8;

  // B fragments in registers: 8 taps x 2 n-tiles, statically indexed
  half8 bfrag[8][2];
#pragma unroll
  for (int tap = 0; tap < 8; ++tap)
#pragma unroll
    for (int t = 0; t < 2; ++t)
      bfrag[tap][t] =
          *(const half8*)(w1p + (size_t)(tap * 32 + t * 16 + lc) * 32 + q * 8);

  // zero the K-pad halfs 24..31 of each As row ONCE (never rewritten)
  if (sseg == 3) *(uint4*)&As[srow * 40 + 24] = make_uint4(0u, 0u, 0u, 0u);

  f32x4 fr0, fr1;
  if (sseg < 3) {
    const f32x4* p = (const f32x4*)aBase;   // tap 0
    fr0 = p[0]; fr1 = p[1];
  }
  f32x4 acc[2];
  acc[0] = (f32x4){0.f, 0.f, 0.f, 0.f};
  acc[1] = (f32x4){0.f, 0.f, 0.f, 0.f};
#pragma unroll
  for (int tap = 0; tap < 8; ++tap) {
    __syncthreads();
    if (sseg < 3) {
      half8 o;
#pragma unroll
      for (int j = 0; j < 4; ++j) {
        o[j] = (half_t)fr0[j];
        o[4 + j] = (half_t)fr1[j];
      }
      *(half8*)&As[srow * 40 + sseg * 8] = o;
    }
    __syncthreads();
    if (tap < 7 && sseg < 3) {              // prefetch next tap row
      const f32x4* p = (const f32x4*)(aBase + (tap + 1) * 252);
      fr0 = p[0]; fr1 = p[1];
    }
    half8 af = *(const half8*)&As[(w * 16 + lc) * 40 + q * 8];
#pragma unroll
    for (int t = 0; t < 2; ++t)
      acc[t] = __builtin_amdgcn_mfma_f32_16x16x32_f16(af, bfrag[tap][t],
                                                      acc[t], 0, 0, 0);
  }
  // C: row=w*16+q*4+r, col=t*16+lc [m89]; out layout [m][32] channels-last
#pragma unroll
  for (int t = 0; t < 2; ++t) {
#pragma unroll
    for (int r = 0; r < 4; ++r) {
      int mr = m0 + w * 16 + q * 4 + r;
      int col = t * 16 + lc;
      out[(size_t)mr * 32 + col] = (half_t)fmaxf(acc[t][r] + b1[col], 0.f);
    }
  }
}

// ---------------- conv2 implicit-GEMM MFMA: -> fp16 [li][9][9][64] ----------
// M-tile 64 x N=64, 4 waves, 16 taps x K=32. A row = in[li][2oy+ky][2ox+kx][:].
__global__ __launch_bounds__(256) void conv2_mfma(
    const half_t* __restrict__ in, const half_t* __restrict__ w2T,
    const float* __restrict__ b2, half_t* __restrict__ out) {
  __shared__ __align__(16) half_t As[64 * 40];
  __shared__ __align__(16) half_t Bs[64 * 40];
  int tid = threadIdx.x;
  int m0 = blockIdx.x * 64;
  int w = tid >> 6, l = tid & 63, lc = l & 15, q = l >> 4;
  int srow = tid >> 2, sseg = tid & 3;
  int m = m0 + srow;
  int li = m / 81, pos = m - li * 81;
  int oy = pos / 9, ox = pos - (pos / 9) * 9;
  const half_t* aBase = in + (size_t)((li * 20 + 2 * oy) * 20 + 2 * ox) * 32 + sseg * 8;
  const half_t* bBase = w2T + srow * 32 + sseg * 8;
  uint4 aReg = *(const uint4*)aBase;          // tap 0
  uint4 bReg = *(const uint4*)bBase;
  f32x4 acc[4];
#pragma unroll
  for (int t = 0; t < 4; ++t) acc[t] = (f32x4){0.f, 0.f, 0.f, 0.f};
#pragma unroll
  for (int tap = 0; tap < 16; ++tap) {
    __syncthreads();
    *(uint4*)&As[srow * 40 + sseg * 8] = aReg;
    *(uint4*)&Bs[srow * 40 + sseg * 8] = bReg;
    __syncthreads();
    if (tap < 15) {                           // prefetch next tap
      int nt = tap + 1, ky = nt >> 2, kx = nt & 3;
      aReg = *(const uint4*)(aBase + (ky * 20 + kx) * 32);
      bReg = *(const uint4*)(bBase + nt * 2048);
    }
    half8 af = *(const half8*)&As[(w * 16 + lc) * 40 + q * 8];
#pragma unroll
    for (int t = 0; t < 4; ++t) {
      half8 bf = *(const half8*)&Bs[(t * 16 + lc) * 40 + q * 8];
      acc[t] = __builtin_amdgcn_mfma_f32_16x16x32_f16(af, bf, acc[t], 0, 0, 0);
    }
  }
  // C: row=w*16+q*4+r, col=t*16+lc [m89]; out offset = m*64+col (layout [m][c])
#pragma unroll
  for (int t = 0; t < 4; ++t) {
#pragma unroll
    for (int r = 0; r < 4; ++r) {
      int mr = m0 + w * 16 + q * 4 + r;
      int col = t * 16 + lc;
      out[(size_t)mr * 64 + col] = (half_t)fmaxf(acc[t][r] + b2[col], 0.f);
    }
  }
}

// ---------------- conv3 implicit-GEMM MFMA: -> fp16 [li][c*49+pos] ----------
// M-tile 64 x N=64, 9 taps x 2 chunks x K=32. A row = in[li][oy+ky][ox+kx][:].
__global__ __launch_bounds__(256) void conv3_mfma(
    const half_t* __restrict__ in, const half_t* __restrict__ w3T,
    const float* __restrict__ b3, half_t* __restrict__ out) {
  __shared__ __align__(16) half_t As[64 * 40];
  __shared__ __align__(16) half_t Bs[64 * 40];
  int tid = threadIdx.x;
  int m0 = blockIdx.x * 64;
  int w = tid >> 6, l = tid & 63, lc = l & 15, q = l >> 4;
  int srow = tid >> 2, sseg = tid & 3;
  int m = m0 + srow;
  int li = m / 49, pos = m - li * 49;
  int oy = pos / 7, ox = pos - (pos / 7) * 7;
  const half_t* aBase = in + (size_t)((li * 9 + oy) * 9 + ox) * 64 + sseg * 8;
  const half_t* bBase = w3T + srow * 64 + sseg * 8;
  uint4 aReg = *(const uint4*)aBase;          // s=0: tap0 chunk0
  uint4 bReg = *(const uint4*)bBase;
  f32x4 acc[4];
#pragma unroll
  for (int t = 0; t < 4; ++t) acc[t] = (f32x4){0.f, 0.f, 0.f, 0.f};
#pragma unroll
  for (int s = 0; s < 18; ++s) {
    __syncthreads();
    *(uint4*)&As[srow * 40 + sseg * 8] = aReg;
    *(uint4*)&Bs[srow * 40 + sseg * 8] = bReg;
    __syncthreads();
    if (s < 17) {                             // prefetch next (tap,chunk)
      int ns = s + 1, tap = ns >> 1, ch = ns & 1;
      int ky = tap / 3, kx = tap - ky * 3;
      aReg = *(const uint4*)(aBase + ((ky * 9 + kx) * 64 + ch * 32));
      bReg = *(const uint4*)(bBase + (tap * 4096 + ch * 32));
    }
    half8 af = *(const half8*)&As[(w * 16 + lc) * 40 + q * 8];
#pragma unroll
    for (int t = 0; t < 4; ++t) {
      half8 bf = *(const half8*)&Bs[(t * 16 + lc) * 40 + q * 8];
      acc[t] = __builtin_amdgcn_mfma_f32_16x16x32_f16(af, bf, acc[t], 0, 0, 0);
    }
  }
  // write k-order c*49+pos (fc_mfma consumes this order; wfcT unchanged)
#pragma unroll
  for (int t = 0; t < 4; ++t) {
#pragma unroll
    for (int r = 0; r < 4; ++r) {
      int mr = m0 + w * 16 + q * 4 + r;
      int li2 = mr / 49, pos2 = mr - li2 * 49;
      int col = t * 16 + lc;
      out[(size_t)li2 * 3136 + col * 49 + pos2] =
          (half_t)fmaxf(acc[t][r] + b3[col], 0.f);
    }
  }
}

// ---------------- FC via MFMA: h = relu(A[2048,3136] @ wfc + bfc) -----------
// Unchanged from R6 (proven). A fp16 rows k=c*49+pos, Bt=wfcT fp16 [512][3136].
__global__ __launch_bounds__(256) void fc_mfma(
    const half_t* __restrict__ A, const half_t* __restrict__ Bt,
    const float* __restrict__ bias, float* __restrict__ C) {
  __shared__ __align__(16) half_t As[64 * 40];
  __shared__ __align__(16) half_t Bs[64 * 40];
  int tid = threadIdx.x;
  int m0 = blockIdx.y * 64, n0 = blockIdx.x * 64;
  int w = tid >> 6;
  int l = tid & 63;
  int lc = l & 15, q = l >> 4;
  int srow = tid >> 2, sseg = tid & 3;

  const half_t* aPtr = A + (size_t)(m0 + srow) * 3136 + sseg * 8;
  const half_t* bPtr = Bt + (size_t)(n0 + srow) * 3136 + sseg * 8;
  uint4 aReg = *(const uint4*)aPtr;
  uint4 bReg = *(const uint4*)bPtr;

  f32x4 acc[4];
#pragma unroll
  for (int t = 0; t < 4; ++t) acc[t] = (f32x4){0.f, 0.f, 0.f, 0.f};

  for (int k0 = 0; k0 < 3136; k0 += 32) {
    __syncthreads();
    *(uint4*)&As[srow * 40 + sseg * 8] = aReg;
    *(uint4*)&Bs[srow * 40 + sseg * 8] = bReg;
    __syncthreads();
    if (k0 + 32 < 3136) {                    // prefetch overlaps MFMA below
      aReg = *(const uint4*)(aPtr + k0 + 32);
      bReg = *(const uint4*)(bPtr + k0 + 32);
    }
    half8 af = *(const half8*)&As[(w * 16 + lc) * 40 + q * 8];
#pragma unroll
    for (int t = 0; t < 4; ++t) {
      half8 bf = *(const half8*)&Bs[(t * 16 + lc) * 40 + q * 8];
      acc[t] = __builtin_amdgcn_mfma_f32_16x16x32_f16(af, bf, acc[t], 0, 0, 0);
    }
  }
#pragma unroll
  for (int t = 0; t < 4; ++t) {
#pragma unroll
    for (int r = 0; r < 4; ++r) {
      int row = m0 + w * 16 + q * 4 + r;
      int col = n0 + t * 16 + lc;
      C[(size_t)row * 512 + col] = fmaxf(acc[t][r] + bias[col], 0.f);
    }
  }
}

// ---------------- wfeat = h @ Ww + bw : [2048,512]@[512,32] ----------------
__global__ __launch_bounds__(256) void wfeat_kernel(
    const float* __restrict__ h, const float* __restrict__ Ww,
    const float* __restrict__ bw, float* __restrict__ wf) {
  int g = blockIdx.x * 256 + threadIdx.x;   // 65536
  int row = g >> 5, oc = g & 31;
  float acc = bw[oc];
  const float* hr = h + (size_t)row * 512;
#pragma unroll 8
  for (int k = 0; k < 512; ++k) acc += hr[k] * Ww[k * 32 + oc];
  wf[g] = acc;
}

// ---------------- posfeat: one-hot MLP, one wave per row ----------------
__global__ __launch_bounds__(256) void posfeat_kernel(
    const int* __restrict__ pos, const float* __restrict__ wp1,
    const float* __restrict__ bp1, const float* __restrict__ wp2,
    const float* __restrict__ bp2, float* __restrict__ pf) {
  int row = (blockIdx.x * 256 + threadIdx.x) >> 6;  // 2048
  int l = threadIdx.x & 63;
  int p0 = pos[row * 2], p1 = pos[row * 2 + 1];
  float t1 = fmaxf(wp1[p0 * 64 + l] + wp1[(16 + p1) * 64 + l] + bp1[l], 0.f);
  float acc = bp2[l];
#pragma unroll
  for (int k = 0; k < 64; ++k) acc += __shfl(t1, k) * wp2[k * 64 + l];
  pf[row * 64 + l] = acc;
}

// ---------------- y0 = state0 @ [wpo1|wv1] : [64,8192]@[8192,128] ----------------
__global__ __launch_bounds__(256) void y0_kernel(
    const float* __restrict__ s0, const float* __restrict__ wpo1,
    const float* __restrict__ wv1, float* __restrict__ y0) {
  int g = blockIdx.x * 256 + threadIdx.x;   // 65536: (b, ks, n)
  int n = g & 127, ks = (g >> 7) & 7, b = g >> 10;
  const float* W = (n < 64) ? (wpo1 + n) : (wv1 + (n - 64));
  const float* s = s0 + (size_t)b * 8192 + ks * 1024;
  float acc = 0.f;
#pragma unroll 4
  for (int j = 0; j < 1024; ++j) acc += s[j] * W[(size_t)(ks * 1024 + j) * 64];
  atomicAdd(y0 + b * 128 + n, acc);
}

// ---------------- ystate: recurrence for hidden@W1 (cols 0..8191) ----------------
__global__ __launch_bounds__(128) void ystate_kernel(
    const float* __restrict__ y0, const float* __restrict__ done,
    const int* __restrict__ pos, const float* __restrict__ wf,
    const float* __restrict__ wpo1, const float* __restrict__ wv1,
    float* __restrict__ ys) {
  int b = blockIdx.x;
  int n = threadIdx.x;                      // 0..127
  const float* W = (n < 64) ? (wpo1 + n) : (wv1 + (n - 64));
  float y = y0[b * 128 + n];
  for (int t = 0; t < TT; ++t) {
    int row = t * BB + b;
    float mask = 1.f - done[row];
    int off = pos[row * 2] * 16 + pos[row * 2 + 1];
    y *= mask;
    const float* wfr = wf + row * 32;
#pragma unroll
    for (int c = 0; c < 32; ++c) y += wfr[c] * W[(size_t)(c * 256 + off) * 64];
    ys[(size_t)row * 128 + n] = y;
  }
}

// ---------------- final map state (output 2) ----------------
__global__ __launch_bounds__(256) void state_kernel(
    const float* __restrict__ s0, const float* __restrict__ done,
    const int* __restrict__ pos, const float* __restrict__ wf,
    float* __restrict__ out_state) {
  int b = blockIdx.x, tid = threadIdx.x;    // tid = spatial offset 0..255
  float s[32];
#pragma unroll
  for (int c = 0; c < 32; ++c) s[c] = s0[(size_t)b * 8192 + c * 256 + tid];
  for (int t = 0; t < TT; ++t) {
    int row = t * BB + b;
    float mask = 1.f - done[row];
    int off = pos[row * 2] * 16 + pos[row * 2 + 1];
#pragma unroll
    for (int c = 0; c < 32; ++c) s[c] *= mask;
    if (tid == off) {
#pragma unroll
      for (int c = 0; c < 32; ++c) s[c] += wf[row * 32 + c];
    }
  }
#pragma unroll
  for (int c = 0; c < 32; ++c) out_state[(size_t)b * 8192 + c * 256 + tid] = s[c];
}

// ---------------- heads: + pos-part of W1, ReLU, second layers ----------------
__global__ __launch_bounds__(256) void head_kernel(
    const float* __restrict__ ys, const float* __restrict__ pf,
    const float* __restrict__ wpo1, const float* __restrict__ wv1,
    const float* __restrict__ bpo1, const float* __restrict__ bv1,
    const float* __restrict__ wpo2, const float* __restrict__ bpo2,
    const float* __restrict__ wv2, const float* __restrict__ bv2,
    float* __restrict__ logits, float* __restrict__ vout) {
  int row = (blockIdx.x * 256 + threadIdx.x) >> 6;  // one wave per row
  int l = threadIdx.x & 63;
  float pfv = pf[row * 64 + l];
  float accp = bpo1[l] + ys[(size_t)row * 128 + l];
  float accv = bv1[l] + ys[(size_t)row * 128 + 64 + l];
#pragma unroll
  for (int k = 0; k < 64; ++k) {
    float pk = __shfl(pfv, k);
    accp += pk * wpo1[(size_t)(8192 + k) * 64 + l];
    accv += pk * wv1[(size_t)(8192 + k) * 64 + l];
  }
  float rp = fmaxf(accp, 0.f), rv = fmaxf(accv, 0.f);
#pragma unroll
  for (int a = 0; a < 5; ++a) {
    float pa = rp * wpo2[l * 5 + a];
#pragma unroll
    for (int m = 32; m >= 1; m >>= 1) pa += __shfl_xor(pa, m);
    if (l == 0) logits[row * 5 + a] = pa + bpo2[a];
  }
  float pv = rv * wv2[l];
#pragma unroll
  for (int m = 32; m >= 1; m >>= 1) pv += __shfl_xor(pv, m);
  if (l == 0) vout[row] = pv + bv2[0];
}

extern "C" void kernel_launch(void* const* d_in, const int* in_sizes, int n_in,
                              void* d_out, int out_size, void* d_ws, size_t ws_size,
                              hipStream_t stream) {
  const float* image = (const float*)d_in[0];
  const float* done = (const float*)d_in[1];
  const float* state0 = (const float*)d_in[2];
  const int* position = (const int*)d_in[3];
  const float* w1 = (const float*)d_in[4];
  const float* b1 = (const float*)d_in[5];
  const float* w2 = (const float*)d_in[6];
  const float* b2 = (const float*)d_in[7];
  const float* w3 = (const float*)d_in[8];
  const float* b3 = (const float*)d_in[9];
  const float* wfc = (const float*)d_in[10];
  const float* bfc = (const float*)d_in[11];
  const float* Ww = (const float*)d_in[12];
  const float* bw = (const float*)d_in[13];
  const float* wp1 = (const float*)d_in[14];
  const float* bp1 = (const float*)d_in[15];
  const float* wp2 = (const float*)d_in[16];
  const float* bp2 = (const float*)d_in[17];
  const float* wpo1 = (const float*)d_in[18];
  const float* bpo1 = (const float*)d_in[19];
  const float* wpo2 = (const float*)d_in[20];
  const float* bpo2 = (const float*)d_in[21];
  const float* wv1 = (const float*)d_in[22];
  const float* bv1 = (const float*)d_in[23];
  const float* wv2 = (const float*)d_in[24];
  const float* bv2 = (const float*)d_in[25];

  float* ws = (float*)d_ws;
  half_t* w1p = (half_t*)(ws + OFF_W1T);
  half_t* w2T = (half_t*)(ws + OFF_W2T);
  half_t* w3T = (half_t*)(ws + OFF_W3T);
  float* wf = ws + OFF_WF;
  float* pfb = ws + OFF_PF;
  float* y0 = ws + OFF_Y0;
  float* ysb = ws + OFF_YS;
  float* h = ws + OFF_H;
  half_t* wfcT = (half_t*)(ws + OFF_WFCT);
  half_t* c3b = (half_t*)(ws + OFF_C3);
  half_t* c2b = (half_t*)(ws + OFF_C2);
  half_t* c1b = (half_t*)(ws + OFF_C1);

  float* out = (float*)d_out;
  float* out_logits = out;            // [2048,5]
  float* out_v = out + 10240;         // [2048,1]
  float* out_state = out + 12288;     // [64,32,16,16]

  // Tier by ws_size (floats): A: CS=2048 no chunk, 95.9 MB;
  //                           B: CS=1024, 69.7 MB; C: CS=512, 56.6 MB.
  int CS;
  if (ws_size >= (size_t)23986176 * 4) CS = 2048;
  else if (ws_size >= (size_t)17432576 * 4) CS = 1024;
  else CS = 512;
  int nc = TBR / CS;

  hipMemsetAsync(y0, 0, 8192 * sizeof(float), stream);
  prep_kernel<<<304, 256, 0, stream>>>(w1, w2, w3, w1p, w2T, w3T);
  prep_wfct<<<dim3(98, 16), 256, 0, stream>>>(wfc, wfcT);

  for (int c = 0; c < nc; ++c) {
    int n0 = c * CS;
    conv1_mfma<<<CS * 400 / 64, 256, 0, stream>>>(image, w1p, b1, c1b, n0);
    conv2_mfma<<<CS * 81 / 64, 256, 0, stream>>>(
        c1b, w2T, b2, c2b + (size_t)n0 * 5184);
  }
  conv3_mfma<<<TBR * 49 / 64, 256, 0, stream>>>(c2b, w3T, b3, c3b);
  fc_mfma<<<dim3(8, 32), 256, 0, stream>>>(c3b, wfcT, bfc, h);
  wfeat_kernel<<<256, 256, 0, stream>>>(h, Ww, bw, wf);
  posfeat_kernel<<<512, 256, 0, stream>>>(position, wp1, bp1, wp2, bp2, pfb);
  y0_kernel<<<256, 256, 0, stream>>>(state0, wpo1, wv1, y0);
  ystate_kernel<<<64, 128, 0, stream>>>(y0, done, position, wf, wpo1, wv1, ysb);
  state_kernel<<<64, 256, 0, stream>>>(state0, done, position, wf, out_state);
  head_kernel<<<512, 256, 0, stream>>>(ysb, pfb, wpo1, wv1, bpo1, bv1,
                                       wpo2, bpo2, wv2, bv2, out_logits, out_v);
}

// Round 2
// 625.167 us; speedup vs baseline: 1.0804x; 1.0360x over previous
//
#include <hip/hip_runtime.h>
#include <hip/hip_bf16.h>

// MapAgent: NatureCNN (3 convs + FC) -> map-write scan -> policy/value heads.
// T=32, B=64, TB=2048.
//
// R9 change (theory: conv1_mfma at 122us was barrier-bound, not memory-bound:
// MfmaUtil 4.3%, VALUBusy 11%, HBM 17% -- all idle. 16 barriers/block with
// only 2 MFMAs between them lockstep the 4 waves against ~500cy load latency.
// Memory floor is ~30-40us):
//  * conv1: stage the ENTIRE K extent (8 taps x 32 = 40KB LDS) with one
//    cooperative pass, ONE barrier, then 16 back-to-back MFMAs from LDS.
//    Each thread owns fixed (row,seg): seg<3 loads 8 img rows x 32B (all
//    issued up front), seg==3 writes the K-pad zeros. B in registers.
//  * conv2/conv3/fc unchanged (measure one change at a time).

#define TT 32
#define BB 64
#define TBR 2048

typedef _Float16 half_t;
typedef __attribute__((ext_vector_type(8))) _Float16 half8;
typedef __attribute__((ext_vector_type(4))) float f32x4;

// ---- workspace offsets (floats) ----
#define OFF_W1T   0u          // 4096    : w1p fp16 [tap8][oc32][k32] zero-pad
#define OFF_W2T   6144u       // 16384   : w2T fp16 [tap16][oc64][c32]
#define OFF_W3T   22528u      // 18432   : w3T fp16 [tap9][oc64][c64]
#define OFF_WF    40960u      // 65536   : wfeat [2048][32]
#define OFF_PF    106496u     // 131072  : posfeat [2048][64]
#define OFF_Y0    237568u     // 8192    : y0 [64][128]
#define OFF_YS    245760u     // 262144  : ystate [2048][128]
#define OFF_H     507904u     // 1048576 : h [2048][512]
#define OFF_WFCT  1556480u    // 802816  : wfcT fp16 [512][3136] (k=c*49+pos)
#define OFF_C3    2359296u    // 3211264 : c3b fp16 [2048][3136]
#define OFF_C2    5570560u    // 5308416 : c2b fp16 [2048][9][9][64]
#define OFF_C1    10878976u   // c1b fp16 [CS][20][20][32]

// ---------------- weight prep ----------------
__global__ __launch_bounds__(256) void prep_kernel(
    const float* __restrict__ w1, const float* __restrict__ w2,
    const float* __restrict__ w3, half_t* __restrict__ w1p,
    half_t* __restrict__ w2T, half_t* __restrict__ w3T) {
  int g = blockIdx.x * 256 + threadIdx.x;   // 77824 total
  if (g < 8192) {
    // w1p[(tap*32+oc)*32+kk], kk = kx*3+c (<24) else 0 ; w1 is [oc][c][ky*8+kx]
    int kk = g & 31, oc = (g >> 5) & 31, tap = g >> 10;
    half_t v = (half_t)0.f;
    if (kk < 24) {
      int kx = kk / 3, c = kk - 3 * kx;
      v = (half_t)(w1[oc * 192 + c * 64 + tap * 8 + kx] * (1.0f / 255.0f));
    }
    w1p[g] = v;
    return;
  }
  int g2 = g - 8192;
  if (g2 < 32768) {                          // w2T[(tap*64+oc)*32+c]
    int c = g2 & 31, oc = (g2 >> 5) & 63, tap = g2 >> 11;
    w2T[g2] = (half_t)w2[oc * 512 + c * 16 + tap];
    return;
  }
  int g3 = g2 - 32768;
  if (g3 < 36864) {                          // w3T[(tap*64+oc)*64+c]
    int c = g3 & 63, oc = (g3 >> 6) & 63, tap = g3 >> 12;
    w3T[g3] = (half_t)w3[oc * 576 + c * 9 + tap];
  }
}

// ---- wfcT[n][k] = (half)wfc[k][n], k = c*49+pos : LDS-tiled transpose ----
__global__ __launch_bounds__(256) void prep_wfct(
    const float* __restrict__ wfc, half_t* __restrict__ wfcT) {
  __shared__ float t[32][33];
  int k0 = blockIdx.x * 32, n0 = blockIdx.y * 32;
  int tx = threadIdx.x & 31, ty = threadIdx.x >> 5;  // ty 0..7
#pragma unroll
  for (int i = 0; i < 4; ++i)
    t[ty + 8 * i][tx] = wfc[(size_t)(k0 + ty + 8 * i) * 512 + n0 + tx];
  __syncthreads();
#pragma unroll
  for (int i = 0; i < 4; ++i)
    wfcT[(size_t)(n0 + ty + 8 * i) * 3136 + k0 + tx] =
        (half_t)t[tx][ty + 8 * i];
}

// ---------------- conv1 implicit-GEMM MFMA: NHWC fp32 -> fp16 [li][20][20][32]
// M-tile 64 x N=32, 4 waves. Full-K staging: As[8tap][64row][40] = 40KB,
// ONE barrier, then 8 taps x 2 n-tiles = 16 MFMAs back-to-back.
// A row (tap ky) = img[li][4oy+ky][4ox..4ox+7][:] : 24 contiguous floats,
// fp32->fp16 during staging; k 24..31 zero (weights also zero-padded).
__global__ __launch_bounds__(256) void conv1_mfma(
    const float* __restrict__ img, const half_t* __restrict__ w1p,
    const float* __restrict__ b1, half_t* __restrict__ out, int n0) {
  __shared__ __align__(16) half_t As[8][64][40];
  int tid = threadIdx.x;
  int m0 = blockIdx.x * 64;
  int w = tid >> 6, l = tid & 63, lc = l & 15, q = l >> 4;

  // staging task: thread owns (srow, seg); loops all 8 taps
  int seg = tid & 3, srow = (tid >> 2) & 63;
  int ms = m0 + srow;
  int lis = ms / 400, poss = ms - lis * 400;
  int oys = poss / 20, oxs = poss - oys * 20;

  if (seg == 3) {
    // K-pad halfs 24..31 of every row: zero once
#pragma unroll
    for (int tap = 0; tap < 8; ++tap)
      *(uint4*)&As[tap][srow][24] = make_uint4(0u, 0u, 0u, 0u);
  } else {
    // float offset: (4oy+tap)*252 + 12*ox + 8*seg -> mult of 4 -> 16B aligned
    const float* aBase =
        img + (size_t)(n0 + lis) * 21168 + (4 * oys) * 252 + oxs * 12 + seg * 8;
    f32x4 fr[8][2];
#pragma unroll
    for (int tap = 0; tap < 8; ++tap) {      // issue all 8x32B loads up front
      const f32x4* p = (const f32x4*)(aBase + tap * 252);
      fr[tap][0] = p[0];
      fr[tap][1] = p[1];
    }
#pragma unroll
    for (int tap = 0; tap < 8; ++tap) {
      half8 o;
#pragma unroll
      for (int j = 0; j < 4; ++j) {
        o[j] = (half_t)fr[tap][0][j];
        o[4 + j] = (half_t)fr[tap][1][j];
      }
      *(half8*)&As[tap][srow][seg * 8] = o;
    }
  }

  // B fragments in registers: 8 taps x 2 n-tiles (w1p 16KB, L2-hot);
  // loaded before the barrier so it overlaps other waves' staging.
  half8 bfrag[8][2];
#pragma unroll
  for (int tap = 0; tap < 8; ++tap)
#pragma unroll
    for (int t = 0; t < 2; ++t)
      bfrag[tap][t] =
          *(const half8*)(w1p + (size_t)(tap * 32 + t * 16 + lc) * 32 + q * 8);

  __syncthreads();                            // the ONLY barrier

  f32x4 acc[2];
  acc[0] = (f32x4){0.f, 0.f, 0.f, 0.f};
  acc[1] = (f32x4){0.f, 0.f, 0.f, 0.f};
#pragma unroll
  for (int tap = 0; tap < 8; ++tap) {
    half8 af = *(const half8*)&As[tap][w * 16 + lc][q * 8];
    acc[0] = __builtin_amdgcn_mfma_f32_16x16x32_f16(af, bfrag[tap][0],
                                                    acc[0], 0, 0, 0);
    acc[1] = __builtin_amdgcn_mfma_f32_16x16x32_f16(af, bfrag[tap][1],
                                                    acc[1], 0, 0, 0);
  }
  // C: row=w*16+q*4+r, col=t*16+lc [m89]; out layout [m][32] channels-last
#pragma unroll
  for (int t = 0; t < 2; ++t) {
#pragma unroll
    for (int r = 0; r < 4; ++r) {
      int mr = m0 + w * 16 + q * 4 + r;
      int col = t * 16 + lc;
      out[(size_t)mr * 32 + col] = (half_t)fmaxf(acc[t][r] + b1[col], 0.f);
    }
  }
}

// ---------------- conv2 implicit-GEMM MFMA: -> fp16 [li][9][9][64] ----------
// M-tile 64 x N=64, 4 waves, 16 taps x K=32. A row = in[li][2oy+ky][2ox+kx][:].
__global__ __launch_bounds__(256) void conv2_mfma(
    const half_t* __restrict__ in, const half_t* __restrict__ w2T,
    const float* __restrict__ b2, half_t* __restrict__ out) {
  __shared__ __align__(16) half_t As[64 * 40];
  __shared__ __align__(16) half_t Bs[64 * 40];
  int tid = threadIdx.x;
  int m0 = blockIdx.x * 64;
  int w = tid >> 6, l = tid & 63, lc = l & 15, q = l >> 4;
  int srow = tid >> 2, sseg = tid & 3;
  int m = m0 + srow;
  int li = m / 81, pos = m - li * 81;
  int oy = pos / 9, ox = pos - (pos / 9) * 9;
  const half_t* aBase = in + (size_t)((li * 20 + 2 * oy) * 20 + 2 * ox) * 32 + sseg * 8;
  const half_t* bBase = w2T + srow * 32 + sseg * 8;
  uint4 aReg = *(const uint4*)aBase;          // tap 0
  uint4 bReg = *(const uint4*)bBase;
  f32x4 acc[4];
#pragma unroll
  for (int t = 0; t < 4; ++t) acc[t] = (f32x4){0.f, 0.f, 0.f, 0.f};
#pragma unroll
  for (int tap = 0; tap < 16; ++tap) {
    __syncthreads();
    *(uint4*)&As[srow * 40 + sseg * 8] = aReg;
    *(uint4*)&Bs[srow * 40 + sseg * 8] = bReg;
    __syncthreads();
    if (tap < 15) {                           // prefetch next tap
      int nt = tap + 1, ky = nt >> 2, kx = nt & 3;
      aReg = *(const uint4*)(aBase + (ky * 20 + kx) * 32);
      bReg = *(const uint4*)(bBase + nt * 2048);
    }
    half8 af = *(const half8*)&As[(w * 16 + lc) * 40 + q * 8];
#pragma unroll
    for (int t = 0; t < 4; ++t) {
      half8 bf = *(const half8*)&Bs[(t * 16 + lc) * 40 + q * 8];
      acc[t] = __builtin_amdgcn_mfma_f32_16x16x32_f16(af, bf, acc[t], 0, 0, 0);
    }
  }
  // C: row=w*16+q*4+r, col=t*16+lc [m89]; out offset = m*64+col (layout [m][c])
#pragma unroll
  for (int t = 0; t < 4; ++t) {
#pragma unroll
    for (int r = 0; r < 4; ++r) {
      int mr = m0 + w * 16 + q * 4 + r;
      int col = t * 16 + lc;
      out[(size_t)mr * 64 + col] = (half_t)fmaxf(acc[t][r] + b2[col], 0.f);
    }
  }
}

// ---------------- conv3 implicit-GEMM MFMA: -> fp16 [li][c*49+pos] ----------
// M-tile 64 x N=64, 9 taps x 2 chunks x K=32. A row = in[li][oy+ky][ox+kx][:].
__global__ __launch_bounds__(256) void conv3_mfma(
    const half_t* __restrict__ in, const half_t* __restrict__ w3T,
    const float* __restrict__ b3, half_t* __restrict__ out) {
  __shared__ __align__(16) half_t As[64 * 40];
  __shared__ __align__(16) half_t Bs[64 * 40];
  int tid = threadIdx.x;
  int m0 = blockIdx.x * 64;
  int w = tid >> 6, l = tid & 63, lc = l & 15, q = l >> 4;
  int srow = tid >> 2, sseg = tid & 3;
  int m = m0 + srow;
  int li = m / 49, pos = m - li * 49;
  int oy = pos / 7, ox = pos - (pos / 7) * 7;
  const half_t* aBase = in + (size_t)((li * 9 + oy) * 9 + ox) * 64 + sseg * 8;
  const half_t* bBase = w3T + srow * 64 + sseg * 8;
  uint4 aReg = *(const uint4*)aBase;          // s=0: tap0 chunk0
  uint4 bReg = *(const uint4*)bBase;
  f32x4 acc[4];
#pragma unroll
  for (int t = 0; t < 4; ++t) acc[t] = (f32x4){0.f, 0.f, 0.f, 0.f};
#pragma unroll
  for (int s = 0; s < 18; ++s) {
    __syncthreads();
    *(uint4*)&As[srow * 40 + sseg * 8] = aReg;
    *(uint4*)&Bs[srow * 40 + sseg * 8] = bReg;
    __syncthreads();
    if (s < 17) {                             // prefetch next (tap,chunk)
      int ns = s + 1, tap = ns >> 1, ch = ns & 1;
      int ky = tap / 3, kx = tap - ky * 3;
      aReg = *(const uint4*)(aBase + ((ky * 9 + kx) * 64 + ch * 32));
      bReg = *(const uint4*)(bBase + (tap * 4096 + ch * 32));
    }
    half8 af = *(const half8*)&As[(w * 16 + lc) * 40 + q * 8];
#pragma unroll
    for (int t = 0; t < 4; ++t) {
      half8 bf = *(const half8*)&Bs[(t * 16 + lc) * 40 + q * 8];
      acc[t] = __builtin_amdgcn_mfma_f32_16x16x32_f16(af, bf, acc[t], 0, 0, 0);
    }
  }
  // write k-order c*49+pos (fc_mfma consumes this order; wfcT unchanged)
#pragma unroll
  for (int t = 0; t < 4; ++t) {
#pragma unroll
    for (int r = 0; r < 4; ++r) {
      int mr = m0 + w * 16 + q * 4 + r;
      int li2 = mr / 49, pos2 = mr - li2 * 49;
      int col = t * 16 + lc;
      out[(size_t)li2 * 3136 + col * 49 + pos2] =
          (half_t)fmaxf(acc[t][r] + b3[col], 0.f);
    }
  }
}

// ---------------- FC via MFMA: h = relu(A[2048,3136] @ wfc + bfc) -----------
// Unchanged from R6 (proven). A fp16 rows k=c*49+pos, Bt=wfcT fp16 [512][3136].
__global__ __launch_bounds__(256) void fc_mfma(
    const half_t* __restrict__ A, const half_t* __restrict__ Bt,
    const float* __restrict__ bias, float* __restrict__ C) {
  __shared__ __align__(16) half_t As[64 * 40];
  __shared__ __align__(16) half_t Bs[64 * 40];
  int tid = threadIdx.x;
  int m0 = blockIdx.y * 64, n0 = blockIdx.x * 64;
  int w = tid >> 6;
  int l = tid & 63;
  int lc = l & 15, q = l >> 4;
  int srow = tid >> 2, sseg = tid & 3;

  const half_t* aPtr = A + (size_t)(m0 + srow) * 3136 + sseg * 8;
  const half_t* bPtr = Bt + (size_t)(n0 + srow) * 3136 + sseg * 8;
  uint4 aReg = *(const uint4*)aPtr;
  uint4 bReg = *(const uint4*)bPtr;

  f32x4 acc[4];
#pragma unroll
  for (int t = 0; t < 4; ++t) acc[t] = (f32x4){0.f, 0.f, 0.f, 0.f};

  for (int k0 = 0; k0 < 3136; k0 += 32) {
    __syncthreads();
    *(uint4*)&As[srow * 40 + sseg * 8] = aReg;
    *(uint4*)&Bs[srow * 40 + sseg * 8] = bReg;
    __syncthreads();
    if (k0 + 32 < 3136) {                    // prefetch overlaps MFMA below
      aReg = *(const uint4*)(aPtr + k0 + 32);
      bReg = *(const uint4*)(bPtr + k0 + 32);
    }
    half8 af = *(const half8*)&As[(w * 16 + lc) * 40 + q * 8];
#pragma unroll
    for (int t = 0; t < 4; ++t) {
      half8 bf = *(const half8*)&Bs[(t * 16 + lc) * 40 + q * 8];
      acc[t] = __builtin_amdgcn_mfma_f32_16x16x32_f16(af, bf, acc[t], 0, 0, 0);
    }
  }
#pragma unroll
  for (int t = 0; t < 4; ++t) {
#pragma unroll
    for (int r = 0; r < 4; ++r) {
      int row = m0 + w * 16 + q * 4 + r;
      int col = n0 + t * 16 + lc;
      C[(size_t)row * 512 + col] = fmaxf(acc[t][r] + bias[col], 0.f);
    }
  }
}

// ---------------- wfeat = h @ Ww + bw : [2048,512]@[512,32] ----------------
__global__ __launch_bounds__(256) void wfeat_kernel(
    const float* __restrict__ h, const float* __restrict__ Ww,
    const float* __restrict__ bw, float* __restrict__ wf) {
  int g = blockIdx.x * 256 + threadIdx.x;   // 65536
  int row = g >> 5, oc = g & 31;
  float acc = bw[oc];
  const float* hr = h + (size_t)row * 512;
#pragma unroll 8
  for (int k = 0; k < 512; ++k) acc += hr[k] * Ww[k * 32 + oc];
  wf[g] = acc;
}

// ---------------- posfeat: one-hot MLP, one wave per row ----------------
__global__ __launch_bounds__(256) void posfeat_kernel(
    const int* __restrict__ pos, const float* __restrict__ wp1,
    const float* __restrict__ bp1, const float* __restrict__ wp2,
    const float* __restrict__ bp2, float* __restrict__ pf) {
  int row = (blockIdx.x * 256 + threadIdx.x) >> 6;  // 2048
  int l = threadIdx.x & 63;
  int p0 = pos[row * 2], p1 = pos[row * 2 + 1];
  float t1 = fmaxf(wp1[p0 * 64 + l] + wp1[(16 + p1) * 64 + l] + bp1[l], 0.f);
  float acc = bp2[l];
#pragma unroll
  for (int k = 0; k < 64; ++k) acc += __shfl(t1, k) * wp2[k * 64 + l];
  pf[row * 64 + l] = acc;
}

// ---------------- y0 = state0 @ [wpo1|wv1] : [64,8192]@[8192,128] ----------------
__global__ __launch_bounds__(256) void y0_kernel(
    const float* __restrict__ s0, const float* __restrict__ wpo1,
    const float* __restrict__ wv1, float* __restrict__ y0) {
  int g = blockIdx.x * 256 + threadIdx.x;   // 65536: (b, ks, n)
  int n = g & 127, ks = (g >> 7) & 7, b = g >> 10;
  const float* W = (n < 64) ? (wpo1 + n) : (wv1 + (n - 64));
  const float* s = s0 + (size_t)b * 8192 + ks * 1024;
  float acc = 0.f;
#pragma unroll 4
  for (int j = 0; j < 1024; ++j) acc += s[j] * W[(size_t)(ks * 1024 + j) * 64];
  atomicAdd(y0 + b * 128 + n, acc);
}

// ---------------- ystate: recurrence for hidden@W1 (cols 0..8191) ----------------
__global__ __launch_bounds__(128) void ystate_kernel(
    const float* __restrict__ y0, const float* __restrict__ done,
    const int* __restrict__ pos, const float* __restrict__ wf,
    const float* __restrict__ wpo1, const float* __restrict__ wv1,
    float* __restrict__ ys) {
  int b = blockIdx.x;
  int n = threadIdx.x;                      // 0..127
  const float* W = (n < 64) ? (wpo1 + n) : (wv1 + (n - 64));
  float y = y0[b * 128 + n];
  for (int t = 0; t < TT; ++t) {
    int row = t * BB + b;
    float mask = 1.f - done[row];
    int off = pos[row * 2] * 16 + pos[row * 2 + 1];
    y *= mask;
    const float* wfr = wf + row * 32;
#pragma unroll
    for (int c = 0; c < 32; ++c) y += wfr[c] * W[(size_t)(c * 256 + off) * 64];
    ys[(size_t)row * 128 + n] = y;
  }
}

// ---------------- final map state (output 2) ----------------
__global__ __launch_bounds__(256) void state_kernel(
    const float* __restrict__ s0, const float* __restrict__ done,
    const int* __restrict__ pos, const float* __restrict__ wf,
    float* __restrict__ out_state) {
  int b = blockIdx.x, tid = threadIdx.x;    // tid = spatial offset 0..255
  float s[32];
#pragma unroll
  for (int c = 0; c < 32; ++c) s[c] = s0[(size_t)b * 8192 + c * 256 + tid];
  for (int t = 0; t < TT; ++t) {
    int row = t * BB + b;
    float mask = 1.f - done[row];
    int off = pos[row * 2] * 16 + pos[row * 2 + 1];
#pragma unroll
    for (int c = 0; c < 32; ++c) s[c] *= mask;
    if (tid == off) {
#pragma unroll
      for (int c = 0; c < 32; ++c) s[c] += wf[row * 32 + c];
    }
  }
#pragma unroll
  for (int c = 0; c < 32; ++c) out_state[(size_t)b * 8192 + c * 256 + tid] = s[c];
}

// ---------------- heads: + pos-part of W1, ReLU, second layers ----------------
__global__ __launch_bounds__(256) void head_kernel(
    const float* __restrict__ ys, const float* __restrict__ pf,
    const float* __restrict__ wpo1, const float* __restrict__ wv1,
    const float* __restrict__ bpo1, const float* __restrict__ bv1,
    const float* __restrict__ wpo2, const float* __restrict__ bpo2,
    const float* __restrict__ wv2, const float* __restrict__ bv2,
    float* __restrict__ logits, float* __restrict__ vout) {
  int row = (blockIdx.x * 256 + threadIdx.x) >> 6;  // one wave per row
  int l = threadIdx.x & 63;
  float pfv = pf[row * 64 + l];
  float accp = bpo1[l] + ys[(size_t)row * 128 + l];
  float accv = bv1[l] + ys[(size_t)row * 128 + 64 + l];
#pragma unroll
  for (int k = 0; k < 64; ++k) {
    float pk = __shfl(pfv, k);
    accp += pk * wpo1[(size_t)(8192 + k) * 64 + l];
    accv += pk * wv1[(size_t)(8192 + k) * 64 + l];
  }
  float rp = fmaxf(accp, 0.f), rv = fmaxf(accv, 0.f);
#pragma unroll
  for (int a = 0; a < 5; ++a) {
    float pa = rp * wpo2[l * 5 + a];
#pragma unroll
    for (int m = 32; m >= 1; m >>= 1) pa += __shfl_xor(pa, m);
    if (l == 0) logits[row * 5 + a] = pa + bpo2[a];
  }
  float pv = rv * wv2[l];
#pragma unroll
  for (int m = 32; m >= 1; m >>= 1) pv += __shfl_xor(pv, m);
  if (l == 0) vout[row] = pv + bv2[0];
}

extern "C" void kernel_launch(void* const* d_in, const int* in_sizes, int n_in,
                              void* d_out, int out_size, void* d_ws, size_t ws_size,
                              hipStream_t stream) {
  const float* image = (const float*)d_in[0];
  const float* done = (const float*)d_in[1];
  const float* state0 = (const float*)d_in[2];
  const int* position = (const int*)d_in[3];
  const float* w1 = (const float*)d_in[4];
  const float* b1 = (const float*)d_in[5];
  const float* w2 = (const float*)d_in[6];
  const float* b2 = (const float*)d_in[7];
  const float* w3 = (const float*)d_in[8];
  const float* b3 = (const float*)d_in[9];
  const float* wfc = (const float*)d_in[10];
  const float* bfc = (const float*)d_in[11];
  const float* Ww = (const float*)d_in[12];
  const float* bw = (const float*)d_in[13];
  const float* wp1 = (const float*)d_in[14];
  const float* bp1 = (const float*)d_in[15];
  const float* wp2 = (const float*)d_in[16];
  const float* bp2 = (const float*)d_in[17];
  const float* wpo1 = (const float*)d_in[18];
  const float* bpo1 = (const float*)d_in[19];
  const float* wpo2 = (const float*)d_in[20];
  const float* bpo2 = (const float*)d_in[21];
  const float* wv1 = (const float*)d_in[22];
  const float* bv1 = (const float*)d_in[23];
  const float* wv2 = (const float*)d_in[24];
  const float* bv2 = (const float*)d_in[25];

  float* ws = (float*)d_ws;
  half_t* w1p = (half_t*)(ws + OFF_W1T);
  half_t* w2T = (half_t*)(ws + OFF_W2T);
  half_t* w3T = (half_t*)(ws + OFF_W3T);
  float* wf = ws + OFF_WF;
  float* pfb = ws + OFF_PF;
  float* y0 = ws + OFF_Y0;
  float* ysb = ws + OFF_YS;
  float* h = ws + OFF_H;
  half_t* wfcT = (half_t*)(ws + OFF_WFCT);
  half_t* c3b = (half_t*)(ws + OFF_C3);
  half_t* c2b = (half_t*)(ws + OFF_C2);
  half_t* c1b = (half_t*)(ws + OFF_C1);

  float* out = (float*)d_out;
  float* out_logits = out;            // [2048,5]
  float* out_v = out + 10240;         // [2048,1]
  float* out_state = out + 12288;     // [64,32,16,16]

  // Tier by ws_size (floats): A: CS=2048 no chunk, 95.9 MB;
  //                           B: CS=1024, 69.7 MB; C: CS=512, 56.6 MB.
  int CS;
  if (ws_size >= (size_t)23986176 * 4) CS = 2048;
  else if (ws_size >= (size_t)17432576 * 4) CS = 1024;
  else CS = 512;
  int nc = TBR / CS;

  hipMemsetAsync(y0, 0, 8192 * sizeof(float), stream);
  prep_kernel<<<304, 256, 0, stream>>>(w1, w2, w3, w1p, w2T, w3T);
  prep_wfct<<<dim3(98, 16), 256, 0, stream>>>(wfc, wfcT);

  for (int c = 0; c < nc; ++c) {
    int n0 = c * CS;
    conv1_mfma<<<CS * 400 / 64, 256, 0, stream>>>(image, w1p, b1, c1b, n0);
    conv2_mfma<<<CS * 81 / 64, 256, 0, stream>>>(
        c1b, w2T, b2, c2b + (size_t)n0 * 5184);
  }
  conv3_mfma<<<TBR * 49 / 64, 256, 0, stream>>>(c2b, w3T, b3, c3b);
  fc_mfma<<<dim3(8, 32), 256, 0, stream>>>(c3b, wfcT, bfc, h);
  wfeat_kernel<<<256, 256, 0, stream>>>(h, Ww, bw, wf);
  posfeat_kernel<<<512, 256, 0, stream>>>(position, wp1, bp1, wp2, bp2, pfb);
  y0_kernel<<<256, 256, 0, stream>>>(state0, wpo1, wv1, y0);
  ystate_kernel<<<64, 128, 0, stream>>>(y0, done, position, wf, wpo1, wv1, ysb);
  state_kernel<<<64, 256, 0, stream>>>(state0, done, position, wf, out_state);
  head_kernel<<<512, 256, 0, stream>>>(ysb, pfb, wpo1, wv1, bpo1, bv1,
                                       wpo2, bpo2, wv2, bv2, out_logits, out_v);
}